// Round 8
// baseline (457.713 us; speedup 1.0000x reference)
//
#include <hip/hip_runtime.h>
#include <math.h>

// ---------------------------------------------------------------------------
// Round 13: chunk-major (conflict-free) LDS layout.
//  R12: decoder_fused 99.7us with 7.5M bank-conflict cycles: [row][32] tiles
//  have 64B rows -> fragment reads are 8-way bank conflicts (bank slot
//  (4r+q)%8 takes 2 values across 16 rows).
//  Fix: store tiles chunk-major [kq][row] (element A[row][k] at
//  kq*ROWS*8 + row*8 + (k&7)): 16-lane groups read 16 CONSECUTIVE 16B
//  chunks -> all 8 bank slots x2 = conflict-free. global_load_lds dest
//  stays lane-linear; only per-lane global source remapped (m173 pattern).
//  Applied to decoder_fused (Ast/W1s/Hb) and mlp2_cs (Ast/Wst/Hc/Hb).
// ---------------------------------------------------------------------------

constexpr int Tn  = 6;
constexpr int Dn  = 256;
constexpr int Hn  = 512;
constexpr int NBn = 5;
constexpr int OUTn = 401;
constexpr int BA  = 8192;
constexpr int MR  = 49152;
constexpr float kAlpha = 0.5f;
constexpr float kBeta  = 0.5f;

typedef __bf16 bf16_8 __attribute__((ext_vector_type(8)));
typedef float  f32x4  __attribute__((ext_vector_type(4)));

__device__ __forceinline__ void async_copy16(const __bf16* g, __bf16* l) {
  __builtin_amdgcn_global_load_lds(
      (const __attribute__((address_space(1))) void*)g,
      (__attribute__((address_space(3))) void*)l, 16, 0, 0);
}

// ---- generic GEMM (tiny anchor GEMMs only), double-buffered ----------------
template<bool RELU, bool OUT_BF16>
__global__ __launch_bounds__(256) void gemm_mfma(
    const __bf16* __restrict__ A, const __bf16* __restrict__ BT,
    const float* __restrict__ bias, void* __restrict__ Cout,
    int M, int N, int K)
{
  __shared__ __align__(16) char smem[34816];

  const int tid = threadIdx.x;
  const int l   = tid & 63;
  const int w   = tid >> 6;
  const int wm  = w >> 1, wn = w & 1;

  const int GX = gridDim.x;
  const int total = GX * gridDim.y;
  const int L = blockIdx.y * GX + blockIdx.x;
  const int xcd = L & 7, pos = L >> 3;
  const int base = total >> 3, rem = total & 7;
  const int start = xcd * base + (xcd < rem ? xcd : rem);
  const int TL = start + pos;
  const int my = TL / GX;
  const int nx = TL - my * GX;
  const int m0 = my * 128;
  const int n0 = nx * 128;

  const int lrow = l >> 2;
  const int lk   = (l & 3) * 8;
  int ar0 = m0 + w * 32 + lrow;        if (ar0 > M - 1) ar0 = M - 1;
  int ar1 = m0 + w * 32 + 16 + lrow;   if (ar1 > M - 1) ar1 = M - 1;
  int br0 = n0 + w * 32 + lrow;        if (br0 > N - 1) br0 = N - 1;
  int br1 = n0 + w * 32 + 16 + lrow;   if (br1 > N - 1) br1 = N - 1;
  const __bf16* Ag0 = A  + (size_t)ar0 * K + lk;
  const __bf16* Ag1 = A  + (size_t)ar1 * K + lk;
  const __bf16* Bg0 = BT + (size_t)br0 * K + lk;
  const __bf16* Bg1 = BT + (size_t)br1 * K + lk;

  f32x4 acc[4][4];
#pragma unroll
  for (int i = 0; i < 4; ++i)
#pragma unroll
    for (int j = 0; j < 4; ++j) acc[i][j] = (f32x4){0.f, 0.f, 0.f, 0.f};

  auto stage = [&](int buf, int ko) {
    __bf16* As = (__bf16*)(smem + buf * 16384);
    __bf16* Bs = As + 4096;
    async_copy16(Ag0 + ko, As + w * 1024);
    async_copy16(Ag1 + ko, As + w * 1024 + 512);
    async_copy16(Bg0 + ko, Bs + w * 1024);
    async_copy16(Bg1 + ko, Bs + w * 1024 + 512);
  };

  const int kIters = K >> 5;
  stage(0, 0);
  __syncthreads();
  for (int kt = 0; kt < kIters; ++kt) {
    if (kt + 1 < kIters) stage((kt + 1) & 1, (kt + 1) * 32);
    const __bf16* As = (const __bf16*)(smem + (kt & 1) * 16384);
    const __bf16* Bs = As + 4096;
    const __bf16* ap = As + (wm * 64 + (l & 15)) * 32 + (l >> 4) * 8;
    const __bf16* bp = Bs + (wn * 64 + (l & 15)) * 32 + (l >> 4) * 8;

    bf16_8 af[4], bf[4];
#pragma unroll
    for (int i = 0; i < 4; ++i) af[i] = *(const bf16_8*)(ap + i * 16 * 32);
#pragma unroll
    for (int j = 0; j < 4; ++j) bf[j] = *(const bf16_8*)(bp + j * 16 * 32);
#pragma unroll
    for (int i = 0; i < 4; ++i)
#pragma unroll
      for (int j = 0; j < 4; ++j)
        acc[i][j] = __builtin_amdgcn_mfma_f32_16x16x32_bf16(af[i], bf[j], acc[i][j], 0, 0, 0);
    __syncthreads();
  }

  const int colb = n0 + wn * 64 + (l & 15);
  const int rowb = m0 + wm * 64 + (l >> 4) * 4;

  if (OUT_BF16) {
    __bf16* Cs = (__bf16*)smem;
    const int lrb = wm * 64 + (l >> 4) * 4;
    const int lcb = wn * 64 + (l & 15);
#pragma unroll
    for (int j = 0; j < 4; ++j) {
      const float bj = bias[colb + j * 16];
#pragma unroll
      for (int i = 0; i < 4; ++i) {
#pragma unroll
        for (int r = 0; r < 4; ++r) {
          float v = acc[i][j][r] + bj;
          if (RELU) v = fmaxf(v, 0.0f);
          Cs[(lrb + i * 16 + r) * 136 + lcb + j * 16] = (__bf16)v;
        }
      }
    }
    __syncthreads();
    __bf16* Cg = (__bf16*)Cout;
#pragma unroll
    for (int it = 0; it < 8; ++it) {
      const int idx = it * 256 + tid;
      const int row = idx >> 4, c16 = idx & 15;
      const int gr = m0 + row;
      if (gr < M) {
        uint4 v = *(const uint4*)(Cs + row * 136 + c16 * 8);
        *(uint4*)(Cg + (size_t)gr * N + n0 + c16 * 8) = v;
      }
    }
  } else {
#pragma unroll
    for (int j = 0; j < 4; ++j) {
      const int gc = colb + j * 16;
      if (gc >= N) continue;
      const float bj = bias[gc];
#pragma unroll
      for (int i = 0; i < 4; ++i) {
        const int gr0 = rowb + i * 16;
#pragma unroll
        for (int r = 0; r < 4; ++r) {
          const int gr = gr0 + r;
          if (gr >= M) continue;
          float v = acc[i][j][r] + bj;
          if (RELU) v = fmaxf(v, 0.0f);
          ((float*)Cout)[(size_t)gr * N + gc] = v;
        }
      }
    }
  }
}

// ---- fused 2-layer c-MLP (iteration 0 only; old layout, unchanged) ---------
__global__ __launch_bounds__(512) void mlp2_c(
    const __bf16* __restrict__ X, const __bf16* __restrict__ W1T,
    const float* __restrict__ b1, const __bf16* __restrict__ W2T,
    const float* __restrict__ b2, __bf16* __restrict__ Out)
{
  __shared__ __align__(16) char smem[53248];
  __bf16* Hb = (__bf16*)(smem + 36864);

  const int tid = threadIdx.x, l = tid & 63, w = tid >> 6;  // w 0..7
  const int m0 = blockIdx.x * 32;
  const int q4 = (l >> 4) * 4;

  f32x4 acc[2][2];
#pragma unroll
  for (int i = 0; i < 2; ++i)
#pragma unroll
    for (int j = 0; j < 2; ++j) acc[i][j] = (f32x4){0.f, 0.f, 0.f, 0.f};

  const __bf16* Xg = X + (size_t)(m0 + (tid >> 2)) * Dn + (tid & 3) * 8; // tid<128

  auto stageA = [&](int buf, int kt) {
    if (tid < 128)
      async_copy16(Xg + kt * 32, (__bf16*)(smem + buf * 2048) + tid * 8);
  };
  auto stageW = [&](const __bf16* WT, int buf, int kt) {
    __bf16* Wstb = (__bf16*)(smem + 4096 + buf * 16384);
#pragma unroll
    for (int r2 = 0; r2 < 2; ++r2) {
      const int ch = tid + r2 * 512, row = ch >> 2, kk = (ch & 3) * 8;
      async_copy16(WT + (size_t)row * Dn + kt * 32 + kk, Wstb + ch * 8);
    }
  };

  // ---- layer 1 ----
  stageA(0, 0); stageW(W1T, 0, 0);
  __syncthreads();
  for (int kt = 0; kt < 8; ++kt) {
    if (kt < 7) { stageA((kt + 1) & 1, kt + 1); stageW(W1T, (kt + 1) & 1, kt + 1); }
    const __bf16* Astb = (const __bf16*)(smem + (kt & 1) * 2048);
    const __bf16* Wstb = (const __bf16*)(smem + 4096 + (kt & 1) * 16384);
    bf16_8 bf[2];
#pragma unroll
    for (int j = 0; j < 2; ++j)
      bf[j] = *(const bf16_8*)(Wstb + (w * 32 + j * 16 + (l & 15)) * 32 + (l >> 4) * 8);
#pragma unroll
    for (int i = 0; i < 2; ++i) {
      bf16_8 af = *(const bf16_8*)(Astb + (i * 16 + (l & 15)) * 32 + (l >> 4) * 8);
#pragma unroll
      for (int j = 0; j < 2; ++j)
        acc[i][j] = __builtin_amdgcn_mfma_f32_16x16x32_bf16(af, bf[j], acc[i][j], 0, 0, 0);
    }
    __syncthreads();
  }

  // h = relu(acc + b1) -> pre-tiled LDS [kt][32][32]
#pragma unroll
  for (int j = 0; j < 2; ++j) {
    const int col = w * 32 + j * 16 + (l & 15);
    const float bj = b1[col];
    __bf16* hc = Hb + (col >> 5) * 1024 + (col & 31);
#pragma unroll
    for (int i = 0; i < 2; ++i)
#pragma unroll
      for (int r = 0; r < 4; ++r) {
        const int row = i * 16 + q4 + r;
        hc[row * 32] = (__bf16)fmaxf(acc[i][j][r] + bj, 0.0f);
      }
  }
  __syncthreads();

  // ---- layer 2 ----
#pragma unroll
  for (int i = 0; i < 2; ++i)
#pragma unroll
    for (int j = 0; j < 2; ++j) acc[i][j] = (f32x4){0.f, 0.f, 0.f, 0.f};
  stageW(W2T, 0, 0);
  __syncthreads();
  for (int kt = 0; kt < 8; ++kt) {
    if (kt < 7) stageW(W2T, (kt + 1) & 1, kt + 1);
    const __bf16* Wstb = (const __bf16*)(smem + 4096 + (kt & 1) * 16384);
    bf16_8 bf[2];
#pragma unroll
    for (int j = 0; j < 2; ++j)
      bf[j] = *(const bf16_8*)(Wstb + (w * 32 + j * 16 + (l & 15)) * 32 + (l >> 4) * 8);
#pragma unroll
    for (int i = 0; i < 2; ++i) {
      bf16_8 af = *(const bf16_8*)(Hb + kt * 1024 + (i * 16 + (l & 15)) * 32 + (l >> 4) * 8);
#pragma unroll
      for (int j = 0; j < 2; ++j)
        acc[i][j] = __builtin_amdgcn_mfma_f32_16x16x32_bf16(af, bf[j], acc[i][j], 0, 0, 0);
    }
    __syncthreads();
  }

#pragma unroll
  for (int j = 0; j < 2; ++j) {
    const int col = w * 32 + j * 16 + (l & 15);
    const float bj = b2[col];
#pragma unroll
    for (int i = 0; i < 2; ++i)
#pragma unroll
      for (int r = 0; r < 4; ++r) {
        const int row = i * 16 + q4 + r;
        Out[(size_t)(m0 + row) * Dn + col] = (__bf16)(acc[i][j][r] + bj);
      }
  }
}

// ---- fused c-MLP + s-MLP + elementwise update (iterations 1..4) ------------
// Chunk-major tiles: element A[row][k] at kq*ROWS*8 + row*8 + (k&7).
__global__ __launch_bounds__(512) void mlp2_cs(
    __bf16* __restrict__ S,
    const __bf16* __restrict__ sW1T, const float* __restrict__ sb1,
    const __bf16* __restrict__ sW2T, const float* __restrict__ sb2,
    const __bf16* __restrict__ cW1T, const float* __restrict__ cb1,
    const __bf16* __restrict__ cW2T, const float* __restrict__ cb2,
    __bf16* __restrict__ C)
{
  __shared__ __align__(16) char smem[71680];
  __bf16* Hb    = (__bf16*)(smem + 22528);
  __bf16* Snew  = (__bf16*)smem;
  __bf16* Hc    = (__bf16*)(smem + 45056);
  __bf16* CnewL = (__bf16*)(smem + 53248);

  const int tid = threadIdx.x, l = tid & 63, w = tid >> 6;  // w 0..7
  const int m0  = blockIdx.x * 96;
  const int ba0 = blockIdx.x * 16;
  const int q4  = (l >> 4) * 4;

  // ===================== Phase C: cnew = mlp_c(C[16 rows]) ==================
  {
    f32x4 ac[2];
    ac[0] = (f32x4){0.f, 0.f, 0.f, 0.f};
    ac[1] = (f32x4){0.f, 0.f, 0.f, 0.f};

    // chunk-major: tile chunk c=tid (<64): kq=tid>>4, row=tid&15
    const __bf16* Cg = C + (size_t)(ba0 + (tid & 15)) * Dn + (tid >> 4) * 8;

    auto stageC1 = [&](int buf, int kt) {
      __bf16* Astb = (__bf16*)(smem + buf * 22528);
      __bf16* Wstb = Astb + 3072;
      if (tid < 64) async_copy16(Cg + kt * 32, Astb + tid * 8);
#pragma unroll
      for (int r2 = 0; r2 < 2; ++r2) {
        const int ch = tid + r2 * 512, row = ch & 255, kq = ch >> 8;
        async_copy16(cW1T + (size_t)row * Dn + kt * 32 + kq * 8, Wstb + ch * 8);
      }
    };
    stageC1(0, 0);
    __syncthreads();
    for (int kt = 0; kt < 8; ++kt) {
      if (kt < 7) stageC1((kt + 1) & 1, kt + 1);
      const __bf16* Astb = (const __bf16*)(smem + (kt & 1) * 22528);
      const __bf16* Wstb = Astb + 3072;
      bf16_8 bf[2];
#pragma unroll
      for (int j = 0; j < 2; ++j)
        bf[j] = *(const bf16_8*)(Wstb + (l >> 4) * 2048 + (w * 32 + j * 16 + (l & 15)) * 8);
      bf16_8 af = *(const bf16_8*)(Astb + (l >> 4) * 128 + (l & 15) * 8);
#pragma unroll
      for (int j = 0; j < 2; ++j)
        ac[j] = __builtin_amdgcn_mfma_f32_16x16x32_bf16(af, bf[j], ac[j], 0, 0, 0);
      __syncthreads();
    }

    // hc = relu(ac + cb1) -> chunk-major [kt][kq][16 rows]
#pragma unroll
    for (int j = 0; j < 2; ++j) {
      const int col = w * 32 + j * 16 + (l & 15);
      const float bj = cb1[col];
      __bf16* hc = Hc + (col >> 5) * 512 + ((col >> 3) & 3) * 128 + (col & 7);
#pragma unroll
      for (int r = 0; r < 4; ++r)
        hc[(q4 + r) * 8] = (__bf16)fmaxf(ac[j][r] + bj, 0.0f);
    }
    __syncthreads();

    ac[0] = (f32x4){0.f, 0.f, 0.f, 0.f};
    ac[1] = (f32x4){0.f, 0.f, 0.f, 0.f};
    auto stageC2 = [&](int buf, int kt) {
      __bf16* Wstb = (__bf16*)(smem + buf * 22528 + 6144);
#pragma unroll
      for (int r2 = 0; r2 < 2; ++r2) {
        const int ch = tid + r2 * 512, row = ch & 255, kq = ch >> 8;
        async_copy16(cW2T + (size_t)row * Dn + kt * 32 + kq * 8, Wstb + ch * 8);
      }
    };
    stageC2(0, 0);
    __syncthreads();
    for (int kt = 0; kt < 8; ++kt) {
      if (kt < 7) stageC2((kt + 1) & 1, kt + 1);
      const __bf16* Wstb = (const __bf16*)(smem + (kt & 1) * 22528 + 6144);
      bf16_8 bf[2];
#pragma unroll
      for (int j = 0; j < 2; ++j)
        bf[j] = *(const bf16_8*)(Wstb + (l >> 4) * 2048 + (w * 32 + j * 16 + (l & 15)) * 8);
      bf16_8 af = *(const bf16_8*)(Hc + kt * 512 + (l >> 4) * 128 + (l & 15) * 8);
#pragma unroll
      for (int j = 0; j < 2; ++j)
        ac[j] = __builtin_amdgcn_mfma_f32_16x16x32_bf16(af, bf[j], ac[j], 0, 0, 0);
      __syncthreads();
    }

    // cnew (bf16, +cb2) -> CnewL [16][264] (update-phase layout, unchanged)
#pragma unroll
    for (int j = 0; j < 2; ++j) {
      const int col = w * 32 + j * 16 + (l & 15);
      const float bj = cb2[col];
#pragma unroll
      for (int r = 0; r < 4; ++r)
        CnewL[(q4 + r) * 264 + col] = (__bf16)(ac[j][r] + bj);
    }
    __syncthreads();
  }

  bf16_8 cn8 = *(const bf16_8*)(CnewL + (tid >> 5) * 264 + (tid & 31) * 8);

  // ===================== Phase S: s-MLP + update ============================
  f32x4 acc[6][2];
#pragma unroll
  for (int i = 0; i < 6; ++i)
#pragma unroll
    for (int j = 0; j < 2; ++j) acc[i][j] = (f32x4){0.f, 0.f, 0.f, 0.f};

  // chunk-major: tile chunk c=tid (<384): kq=tid/96, row=tid%96
  const __bf16* Sg = S + (size_t)(m0 + (tid % 96)) * Dn + (tid / 96) * 8;

  auto stageL1 = [&](int buf, int kt) {
    __bf16* Astb = (__bf16*)(smem + buf * 22528);
    __bf16* Wstb = (__bf16*)(smem + buf * 22528 + 6144);
    if (tid < 384) async_copy16(Sg + kt * 32, Astb + tid * 8);
#pragma unroll
    for (int r2 = 0; r2 < 2; ++r2) {
      const int ch = tid + r2 * 512, row = ch & 255, kq = ch >> 8;
      async_copy16(sW1T + (size_t)row * Dn + kt * 32 + kq * 8, Wstb + ch * 8);
    }
  };

  stageL1(0, 0);
  __syncthreads();
  for (int kt = 0; kt < 8; ++kt) {
    if (kt < 7) stageL1((kt + 1) & 1, kt + 1);
    const __bf16* Astb = (const __bf16*)(smem + (kt & 1) * 22528);
    const __bf16* Wstb = Astb + 3072;
    bf16_8 bf[2];
#pragma unroll
    for (int j = 0; j < 2; ++j)
      bf[j] = *(const bf16_8*)(Wstb + (l >> 4) * 2048 + (w * 32 + j * 16 + (l & 15)) * 8);
#pragma unroll
    for (int i = 0; i < 6; ++i) {
      bf16_8 af = *(const bf16_8*)(Astb + (l >> 4) * 768 + (i * 16 + (l & 15)) * 8);
#pragma unroll
      for (int j = 0; j < 2; ++j)
        acc[i][j] = __builtin_amdgcn_mfma_f32_16x16x32_bf16(af, bf[j], acc[i][j], 0, 0, 0);
    }
    __syncthreads();
  }

  // h = relu(acc + sb1) -> chunk-major [kt][kq][96 rows]
#pragma unroll
  for (int j = 0; j < 2; ++j) {
    const int col = w * 32 + j * 16 + (l & 15);
    const float bj = sb1[col];
    __bf16* hc = Hb + (col >> 5) * 3072 + ((col >> 3) & 3) * 768 + (col & 7);
#pragma unroll
    for (int i = 0; i < 6; ++i)
#pragma unroll
      for (int r = 0; r < 4; ++r) {
        const int row = i * 16 + q4 + r;
        hc[row * 8] = (__bf16)fmaxf(acc[i][j][r] + bj, 0.0f);
      }
  }
  __syncthreads();

#pragma unroll
  for (int i = 0; i < 6; ++i)
#pragma unroll
    for (int j = 0; j < 2; ++j) acc[i][j] = (f32x4){0.f, 0.f, 0.f, 0.f};
  __bf16* Wst = (__bf16*)(smem + 6144);
  for (int kt = 0; kt < 8; ++kt) {
#pragma unroll
    for (int r2 = 0; r2 < 2; ++r2) {
      const int ch = tid + r2 * 512, row = ch & 255, kq = ch >> 8;
      async_copy16(sW2T + (size_t)row * Dn + kt * 32 + kq * 8, Wst + ch * 8);
    }
    __syncthreads();
    bf16_8 bf[2];
#pragma unroll
    for (int j = 0; j < 2; ++j)
      bf[j] = *(const bf16_8*)(Wst + (l >> 4) * 2048 + (w * 32 + j * 16 + (l & 15)) * 8);
#pragma unroll
    for (int i = 0; i < 6; ++i) {
      bf16_8 af = *(const bf16_8*)(Hb + kt * 3072 + (l >> 4) * 768 + (i * 16 + (l & 15)) * 8);
#pragma unroll
      for (int j = 0; j < 2; ++j)
        acc[i][j] = __builtin_amdgcn_mfma_f32_16x16x32_bf16(af, bf[j], acc[i][j], 0, 0, 0);
    }
    __syncthreads();
  }

  // snew (raw, +sb2) -> LDS (stride 264, update-phase layout, unchanged)
#pragma unroll
  for (int j = 0; j < 2; ++j) {
    const int col = w * 32 + j * 16 + (l & 15);
    const float bj = sb2[col];
#pragma unroll
    for (int i = 0; i < 6; ++i)
#pragma unroll
      for (int r = 0; r < 4; ++r) {
        const int row = i * 16 + q4 + r;
        Snew[row * 264 + col] = (__bf16)(acc[i][j][r] + bj);
      }
  }
  __syncthreads();

  {
    const int ba = tid >> 5, dg = (tid & 31) * 8;
    const size_t gb = (size_t)(ba0 + ba) * Dn + dg;
    float cn[8], m[8];
#pragma unroll
    for (int e = 0; e < 8; ++e) { cn[e] = (float)cn8[e]; m[e] = -3.402823466e38f; }
#pragma unroll
    for (int t = 0; t < Tn; ++t) {
      const int row = ba * 6 + t;
      bf16_8 sn8 = *(const bf16_8*)(Snew + row * 264 + dg);
      const size_t gs = (size_t)(m0 + row) * Dn + dg;
      bf16_8 s8 = *(const bf16_8*)(S + gs);
      bf16_8 o8;
#pragma unroll
      for (int e = 0; e < 8; ++e) {
        const float sn = (float)sn8[e] * cn[e];
        m[e] = fmaxf(m[e], sn);
        o8[e] = (__bf16)(kAlpha * (float)s8[e] + kBeta * sn);
      }
      *(bf16_8*)(S + gs) = o8;
    }
    bf16_8 c8 = *(const bf16_8*)(C + gb);
#pragma unroll
    for (int e = 0; e < 8; ++e)
      c8[e] = (__bf16)(kAlpha * (float)c8[e] + kBeta * m[e]);
    *(bf16_8*)(C + gb) = c8;
  }
}

// ---- fully fused decoder v3: chunk-major LDS tiles (conflict-free) ---------
// BM=64, 512 thr, grid 768, launch_bounds(512,4), LDS 72KB -> 2 blocks/CU.
__global__ __launch_bounds__(512, 4) void decoder_fused(
    const __bf16* __restrict__ S, const __bf16* __restrict__ W1T,
    const float* __restrict__ b1, const __bf16* __restrict__ W2T,
    const float* __restrict__ bias, float* __restrict__ out)
{
  __shared__ __align__(16) char smem[73728];
  __bf16* Ast = (__bf16*)smem;             // [8kt][4kq][64row]  32KB (S tile)
  __bf16* W1s = (__bf16*)(smem + 32768);   // [8kt][4kq][64row]  32KB (W1 chunk)
  __bf16* Hb  = (__bf16*)(smem + 65536);   // [2kt2][4kq][64row]  8KB
  float*  mid = (float*)smem;              // epilogue overlay

  const int tid = threadIdx.x, l = tid & 63, w = tid >> 6;  // w 0..7
  const int m0 = blockIdx.x * 64;
  const int q4 = (l >> 4) * 4;
  const int rt  = w >> 1;                  // L1 row-tile (0..3)
  const int ch2 = (w & 1) * 32;            // L1 col-half base

  f32x4 acc[4][4];                         // persistent 64x512 output tile
#pragma unroll
  for (int i = 0; i < 4; ++i)
#pragma unroll
    for (int j = 0; j < 4; ++j) acc[i][j] = (f32x4){0.f, 0.f, 0.f, 0.f};

  // stage whole S tile chunk-major: LDS chunk q: kt=q>>8, kq=(q>>6)&3, row=q&63
#pragma unroll
  for (int r4 = 0; r4 < 4; ++r4) {
    const int q = tid + r4 * 512;
    const int ktq = q >> 8, row = q & 63, kq = (q >> 6) & 3;
    async_copy16(S + (size_t)(m0 + row) * Dn + ktq * 32 + kq * 8, Ast + q * 8);
  }

  auto stageW1 = [&](int cc) {
#pragma unroll
    for (int r4 = 0; r4 < 4; ++r4) {
      const int q = tid + r4 * 512;
      const int ktq = q >> 8, row = q & 63, kq = (q >> 6) & 3;
      async_copy16(W1T + (size_t)(cc * 64 + row) * Dn + ktq * 32 + kq * 8, W1s + q * 8);
    }
  };

  // fixed per-thread W2T column pointers (4 output cols per thread)
  const __bf16* W2p[4];
#pragma unroll
  for (int j = 0; j < 4; ++j) {
    int col = w * 64 + j * 16 + (l & 15);
    if (col > 400) col = 400;
    W2p[j] = W2T + (size_t)col * Hn + (l >> 4) * 8;
  }

  stageW1(0);
  __syncthreads();                          // Ast + W1s(0) resident

  for (int cc = 0; cc < 8; ++cc) {
    // ---- L1: 16 barrier-free MFMAs (conflict-free chunk-major reads) ----
    f32x4 a1[2];
    a1[0] = (f32x4){0.f, 0.f, 0.f, 0.f};
    a1[1] = (f32x4){0.f, 0.f, 0.f, 0.f};
#pragma unroll
    for (int kt = 0; kt < 8; ++kt) {
      bf16_8 af = *(const bf16_8*)(Ast + kt * 2048 + (l >> 4) * 512 + (rt * 16 + (l & 15)) * 8);
#pragma unroll
      for (int j = 0; j < 2; ++j) {
        bf16_8 bw = *(const bf16_8*)(W1s + kt * 2048 + (l >> 4) * 512 + (ch2 + j * 16 + (l & 15)) * 8);
        a1[j] = __builtin_amdgcn_mfma_f32_16x16x32_bf16(af, bw, a1[j], 0, 0, 0);
      }
    }

    // Hb write (bias + relu), chunk-major [kt2][kq][64row]
#pragma unroll
    for (int j = 0; j < 2; ++j) {
      const int col = ch2 + j * 16 + (l & 15);
      const float bj = b1[cc * 64 + col];
      __bf16* hp = Hb + (col >> 5) * 2048 + ((col >> 3) & 3) * 512 + (col & 7);
#pragma unroll
      for (int r = 0; r < 4; ++r)
        hp[(rt * 16 + q4 + r) * 8] = (__bf16)fmaxf(a1[j][r] + bj, 0.0f);
    }
    __syncthreads();                        // (A) W1s free; Hb visible

    if (cc < 7) stageW1(cc + 1);            // async, hidden under L2

    // ---- L2 partial accumulate (K=64); B-frags from L2-hot W2T ----
#pragma unroll
    for (int kt2 = 0; kt2 < 2; ++kt2) {
      bf16_8 af2[4], bf2[4];
#pragma unroll
      for (int j = 0; j < 4; ++j)
        bf2[j] = *(const bf16_8*)(W2p[j] + cc * 64 + kt2 * 32);
#pragma unroll
      for (int i = 0; i < 4; ++i)
        af2[i] = *(const bf16_8*)(Hb + kt2 * 2048 + (l >> 4) * 512 + (i * 16 + (l & 15)) * 8);
#pragma unroll
      for (int i = 0; i < 4; ++i)
#pragma unroll
        for (int j = 0; j < 4; ++j)
          acc[i][j] = __builtin_amdgcn_mfma_f32_16x16x32_bf16(af2[i], bf2[j], acc[i][j], 0, 0, 0);
    }
    __syncthreads();                        // (B) Hb reads done; W1s(cc+1) drained
  }

  // ---- epilogue (unchanged) ----
  float* cov = out + MR + (size_t)MR * 160;
  const int gc = w * 64 + (l & 15);
#pragma unroll
  for (int sub = 0; sub < 2; ++sub) {
#pragma unroll
    for (int ih = 0; ih < 2; ++ih) {
      const int i = sub * 2 + ih;
#pragma unroll
      for (int j = 0; j < 4; ++j) {
        const int c = gc + j * 16;
        if (c > 400) continue;
        const float bj = bias[c];
#pragma unroll
        for (int r = 0; r < 4; ++r) {
          const int lr = ih * 16 + q4 + r;
          const int gr = m0 + sub * 32 + lr;
          const float v = acc[i][j][r] + bj;
          if (c < 160)      out[(size_t)MR + (size_t)gr * 160 + c] = v;
          else if (c < 400) mid[lr * 241 + (c - 160)] = v;
          else              out[gr] = v;
        }
      }
    }
    __syncthreads();
#pragma unroll
    for (int p = 0; p < 5; ++p) {
      const int q = p * 512 + tid;
      const int r32 = q / 80, j = q - r32 * 80;
      const int gr = m0 + sub * 32 + r32;
      const float av = mid[r32 * 241 + j];
      const float bv = mid[r32 * 241 + 80 + j];
      const float cv = mid[r32 * 241 + 160 + j];
      const float eb = __expf(bv), ebn = __expf(-bv);
      const float sh = 0.5f * (eb - ebn), ch = 0.5f * (eb + ebn);
      const float ea = __expf(av), ean = __expf(-av), ec = __expf(cv);
      f32x4 c4 = { ea * ch * ec, sh * ec, sh * ec, ean * ch * ec };
      *(f32x4*)(cov + (size_t)gr * 320 + 4 * j) = c4;
    }
    if (sub == 0) __syncthreads();
  }
}

// ---- weight transpose + bf16 convert ---------------------------------------
__global__ __launch_bounds__(256) void transpose_bf16(
    const float* __restrict__ W, __bf16* __restrict__ WT, int K, int N)
{
  __shared__ float t[32][33];
  const int b  = blockIdx.z;
  const int tx = threadIdx.x, ty = threadIdx.y;
  const int k0 = blockIdx.y * 32, n0 = blockIdx.x * 32;
  const float* Wb  = W  + (size_t)b * K * N;
  __bf16*      WTb = WT + (size_t)b * N * K;
#pragma unroll
  for (int r = 0; r < 4; ++r) {
    int kk = k0 + ty + r * 8;
    if (kk < K && n0 + tx < N) t[ty + r * 8][tx] = Wb[(size_t)kk * N + n0 + tx];
  }
  __syncthreads();
#pragma unroll
  for (int r = 0; r < 4; ++r) {
    int nn = n0 + ty + r * 8;
    if (nn < N && k0 + tx < K)
      WTb[(size_t)nn * K + k0 + tx] = (__bf16)t[tx][ty + r * 8];
  }
}

__global__ __launch_bounds__(256) void convert_bf16(
    const float* __restrict__ in, __bf16* __restrict__ out, int n)
{
  int i = blockIdx.x * 256 + threadIdx.x;
  if (i < n) out[i] = (__bf16)in[i];
}

// ---- iter-0 elementwise (init folded) --------------------------------------
__global__ __launch_bounds__(256) void ew_update0(
    const float* __restrict__ anchor, const float* __restrict__ fe,
    const float* __restrict__ snewsm, const __bf16* __restrict__ cnew,
    __bf16* __restrict__ s, __bf16* __restrict__ c)
{
  int q = blockIdx.x * 256 + threadIdx.x;
  if (q >= BA * 32) return;
  int ba = q >> 5;
  int dg = (q & 31) * 8;
  bf16_8 cn8 = *(const bf16_8*)(cnew + (size_t)ba * Dn + dg);
  float cn[8], m[8];
#pragma unroll
  for (int e = 0; e < 8; ++e) { cn[e] = (float)cn8[e]; m[e] = -3.402823466e38f; }
  size_t base = (size_t)ba * Tn * Dn + dg;
#pragma unroll
  for (int t = 0; t < Tn; ++t) {
    bf16_8 o8;
#pragma unroll
    for (int e = 0; e < 8; ++e) {
      float sn = snewsm[t * Dn + dg + e] * cn[e];
      m[e] = fmaxf(m[e], sn);
      o8[e] = (__bf16)(kAlpha * anchor[t * Dn + dg + e] + kBeta * sn);
    }
    *(bf16_8*)(s + base + t * Dn) = o8;
  }
  bf16_8 c8;
#pragma unroll
  for (int e = 0; e < 8; ++e)
    c8[e] = (__bf16)(kAlpha * fe[(size_t)ba * Dn + dg + e] + kBeta * m[e]);
  *(bf16_8*)(c + (size_t)ba * Dn + dg) = c8;
}

// ---------------------------------------------------------------------------
extern "C" void kernel_launch(void* const* d_in, const int* in_sizes, int n_in,
                              void* d_out, int out_size, void* d_ws, size_t ws_size,
                              hipStream_t stream) {
  const float* fe     = (const float*)d_in[0];
  const float* anchor = (const float*)d_in[1];
  const float* sW1 = (const float*)d_in[2];
  const float* sb1 = (const float*)d_in[3];
  const float* sW2 = (const float*)d_in[4];
  const float* sb2 = (const float*)d_in[5];
  const float* cW1 = (const float*)d_in[6];
  const float* cb1 = (const float*)d_in[7];
  const float* cW2 = (const float*)d_in[8];
  const float* cb2 = (const float*)d_in[9];
  const float* dW1 = (const float*)d_in[10];
  const float* db1 = (const float*)d_in[11];
  const float* dW2 = (const float*)d_in[12];
  const float* db2 = (const float*)d_in[13];
  float* out = (float*)d_out;

  // ---- workspace layout (bytes) ----
  char* p = (char*)d_ws;
  __bf16* s_bf    = (__bf16*)(p + 0);            // 25,165,824
  __bf16* c_bf    = (__bf16*)(p + 75497472);     //  4,194,304
  __bf16* cnew_bf = (__bf16*)(p + 79691776);     //  4,194,304
  __bf16* fe_bf   = (__bf16*)(p + 83886080);     //  4,194,304
  __bf16* sWT1    = (__bf16*)(p + 88080384);     //    655,360 each
  __bf16* sWT2    = (__bf16*)(p + 88735744);
  __bf16* cWT1    = (__bf16*)(p + 89391104);
  __bf16* cWT2    = (__bf16*)(p + 90046464);
  __bf16* dWT1    = (__bf16*)(p + 90701824);     //    262,144
  __bf16* dWT2    = (__bf16*)(p + 90963968);     //    410,624
  __bf16* anc_bf  = (__bf16*)(p + 91374592);     //      3,072
  __bf16* hsm_bf  = (__bf16*)(p + 91377664);     //      3,072
  float*  snewsm_f= (float* )(p + 91380736);     //      6,144

  auto gemm = [&](const __bf16* A, const __bf16* BT, const float* b, void* C,
                  int M, int N, int K, bool relu, bool outbf) {
    dim3 grid((N + 127) / 128, (M + 127) / 128);
    if (relu) {
      if (outbf) gemm_mfma<true,  true ><<<grid, 256, 0, stream>>>(A, BT, b, C, M, N, K);
      else       gemm_mfma<true,  false><<<grid, 256, 0, stream>>>(A, BT, b, C, M, N, K);
    } else {
      if (outbf) gemm_mfma<false, true ><<<grid, 256, 0, stream>>>(A, BT, b, C, M, N, K);
      else       gemm_mfma<false, false><<<grid, 256, 0, stream>>>(A, BT, b, C, M, N, K);
    }
  };

  // ---- weight prep ----
  {
    dim3 blk(32, 8);
    dim3 g88(8, 8, NBn);
    transpose_bf16<<<g88, blk, 0, stream>>>(sW1, sWT1, Dn, Dn);
    transpose_bf16<<<g88, blk, 0, stream>>>(sW2, sWT2, Dn, Dn);
    transpose_bf16<<<g88, blk, 0, stream>>>(cW1, cWT1, Dn, Dn);
    transpose_bf16<<<g88, blk, 0, stream>>>(cW2, cWT2, Dn, Dn);
    transpose_bf16<<<dim3(16, 8, 1), blk, 0, stream>>>(dW1, dWT1, Dn, Hn);
    transpose_bf16<<<dim3(13, 16, 1), blk, 0, stream>>>(dW2, dWT2, Hn, OUTn);
  }
  convert_bf16<<<(BA * Dn + 255) / 256, 256, 0, stream>>>(fe, fe_bf, BA * Dn);
  convert_bf16<<<(Tn * Dn + 255) / 256, 256, 0, stream>>>(anchor, anc_bf, Tn * Dn);

  const size_t WKK = (size_t)Dn * Dn;

  // ---- iteration 0 (s-branch on 6 anchor rows; c-branch fused MLP) ----
  gemm(anc_bf, sWT1, sb1, hsm_bf,   Tn, Dn, Dn, true,  true);
  gemm(hsm_bf, sWT2, sb2, snewsm_f, Tn, Dn, Dn, false, false);
  mlp2_c<<<BA / 32, 512, 0, stream>>>(fe_bf, cWT1, cb1, cWT2, cb2, cnew_bf);
  ew_update0<<<(BA * 32 + 255) / 256, 256, 0, stream>>>(anchor, fe, snewsm_f,
                                                        cnew_bf, s_bf, c_bf);

  // ---- iterations 1..4: ONE fused kernel each ----
  for (int i = 1; i < NBn; ++i) {
    mlp2_cs<<<MR / 96, 512, 0, stream>>>(
        s_bf,
        sWT1 + i * WKK, sb1 + i * Dn, sWT2 + i * WKK, sb2 + i * Dn,
        cWT1 + i * WKK, cb1 + i * Dn, cWT2 + i * WKK, cb2 + i * Dn,
        c_bf);
  }

  // ---- fully fused decoder ----
  decoder_fused<<<MR / 64, 512, 0, stream>>>(s_bf, dWT1, db1, dWT2, db2, out);
}

// Round 9
// 377.606 us; speedup vs baseline: 1.2121x; 1.2121x over previous
//
#include <hip/hip_runtime.h>
#include <math.h>

// ---------------------------------------------------------------------------
// Round 14: revert R13's chunk-major experiment (it fixed LDS conflicts but
// broke GLOBAL coalescing in mlp2_cs: 16B/512B-stride staging, +79us total;
// decoder dur unchanged -> conflicts weren't the critical path).
// Base = R12 (row-major). New: decoder_fused epilogue v2 — coordinates
// staged in LDS (dead W1s region) and written as coalesced f32x4 640B runs
// instead of scalar 4B stores in 64B segments (31.5MB region).
// ---------------------------------------------------------------------------

constexpr int Tn  = 6;
constexpr int Dn  = 256;
constexpr int Hn  = 512;
constexpr int NBn = 5;
constexpr int OUTn = 401;
constexpr int BA  = 8192;
constexpr int MR  = 49152;
constexpr float kAlpha = 0.5f;
constexpr float kBeta  = 0.5f;

typedef __bf16 bf16_8 __attribute__((ext_vector_type(8)));
typedef float  f32x4  __attribute__((ext_vector_type(4)));

__device__ __forceinline__ void async_copy16(const __bf16* g, __bf16* l) {
  __builtin_amdgcn_global_load_lds(
      (const __attribute__((address_space(1))) void*)g,
      (__attribute__((address_space(3))) void*)l, 16, 0, 0);
}

// ---- generic GEMM (tiny anchor GEMMs only), double-buffered ----------------
template<bool RELU, bool OUT_BF16>
__global__ __launch_bounds__(256) void gemm_mfma(
    const __bf16* __restrict__ A, const __bf16* __restrict__ BT,
    const float* __restrict__ bias, void* __restrict__ Cout,
    int M, int N, int K)
{
  __shared__ __align__(16) char smem[34816];

  const int tid = threadIdx.x;
  const int l   = tid & 63;
  const int w   = tid >> 6;
  const int wm  = w >> 1, wn = w & 1;

  const int GX = gridDim.x;
  const int total = GX * gridDim.y;
  const int L = blockIdx.y * GX + blockIdx.x;
  const int xcd = L & 7, pos = L >> 3;
  const int base = total >> 3, rem = total & 7;
  const int start = xcd * base + (xcd < rem ? xcd : rem);
  const int TL = start + pos;
  const int my = TL / GX;
  const int nx = TL - my * GX;
  const int m0 = my * 128;
  const int n0 = nx * 128;

  const int lrow = l >> 2;
  const int lk   = (l & 3) * 8;
  int ar0 = m0 + w * 32 + lrow;        if (ar0 > M - 1) ar0 = M - 1;
  int ar1 = m0 + w * 32 + 16 + lrow;   if (ar1 > M - 1) ar1 = M - 1;
  int br0 = n0 + w * 32 + lrow;        if (br0 > N - 1) br0 = N - 1;
  int br1 = n0 + w * 32 + 16 + lrow;   if (br1 > N - 1) br1 = N - 1;
  const __bf16* Ag0 = A  + (size_t)ar0 * K + lk;
  const __bf16* Ag1 = A  + (size_t)ar1 * K + lk;
  const __bf16* Bg0 = BT + (size_t)br0 * K + lk;
  const __bf16* Bg1 = BT + (size_t)br1 * K + lk;

  f32x4 acc[4][4];
#pragma unroll
  for (int i = 0; i < 4; ++i)
#pragma unroll
    for (int j = 0; j < 4; ++j) acc[i][j] = (f32x4){0.f, 0.f, 0.f, 0.f};

  auto stage = [&](int buf, int ko) {
    __bf16* As = (__bf16*)(smem + buf * 16384);
    __bf16* Bs = As + 4096;
    async_copy16(Ag0 + ko, As + w * 1024);
    async_copy16(Ag1 + ko, As + w * 1024 + 512);
    async_copy16(Bg0 + ko, Bs + w * 1024);
    async_copy16(Bg1 + ko, Bs + w * 1024 + 512);
  };

  const int kIters = K >> 5;
  stage(0, 0);
  __syncthreads();
  for (int kt = 0; kt < kIters; ++kt) {
    if (kt + 1 < kIters) stage((kt + 1) & 1, (kt + 1) * 32);
    const __bf16* As = (const __bf16*)(smem + (kt & 1) * 16384);
    const __bf16* Bs = As + 4096;
    const __bf16* ap = As + (wm * 64 + (l & 15)) * 32 + (l >> 4) * 8;
    const __bf16* bp = Bs + (wn * 64 + (l & 15)) * 32 + (l >> 4) * 8;

    bf16_8 af[4], bf[4];
#pragma unroll
    for (int i = 0; i < 4; ++i) af[i] = *(const bf16_8*)(ap + i * 16 * 32);
#pragma unroll
    for (int j = 0; j < 4; ++j) bf[j] = *(const bf16_8*)(bp + j * 16 * 32);
#pragma unroll
    for (int i = 0; i < 4; ++i)
#pragma unroll
      for (int j = 0; j < 4; ++j)
        acc[i][j] = __builtin_amdgcn_mfma_f32_16x16x32_bf16(af[i], bf[j], acc[i][j], 0, 0, 0);
    __syncthreads();
  }

  const int colb = n0 + wn * 64 + (l & 15);
  const int rowb = m0 + wm * 64 + (l >> 4) * 4;

  if (OUT_BF16) {
    __bf16* Cs = (__bf16*)smem;
    const int lrb = wm * 64 + (l >> 4) * 4;
    const int lcb = wn * 64 + (l & 15);
#pragma unroll
    for (int j = 0; j < 4; ++j) {
      const float bj = bias[colb + j * 16];
#pragma unroll
      for (int i = 0; i < 4; ++i) {
#pragma unroll
        for (int r = 0; r < 4; ++r) {
          float v = acc[i][j][r] + bj;
          if (RELU) v = fmaxf(v, 0.0f);
          Cs[(lrb + i * 16 + r) * 136 + lcb + j * 16] = (__bf16)v;
        }
      }
    }
    __syncthreads();
    __bf16* Cg = (__bf16*)Cout;
#pragma unroll
    for (int it = 0; it < 8; ++it) {
      const int idx = it * 256 + tid;
      const int row = idx >> 4, c16 = idx & 15;
      const int gr = m0 + row;
      if (gr < M) {
        uint4 v = *(const uint4*)(Cs + row * 136 + c16 * 8);
        *(uint4*)(Cg + (size_t)gr * N + n0 + c16 * 8) = v;
      }
    }
  } else {
#pragma unroll
    for (int j = 0; j < 4; ++j) {
      const int gc = colb + j * 16;
      if (gc >= N) continue;
      const float bj = bias[gc];
#pragma unroll
      for (int i = 0; i < 4; ++i) {
        const int gr0 = rowb + i * 16;
#pragma unroll
        for (int r = 0; r < 4; ++r) {
          const int gr = gr0 + r;
          if (gr >= M) continue;
          float v = acc[i][j][r] + bj;
          if (RELU) v = fmaxf(v, 0.0f);
          ((float*)Cout)[(size_t)gr * N + gc] = v;
        }
      }
    }
  }
}

// ---- fused 2-layer c-MLP (iteration 0 only) --------------------------------
__global__ __launch_bounds__(512) void mlp2_c(
    const __bf16* __restrict__ X, const __bf16* __restrict__ W1T,
    const float* __restrict__ b1, const __bf16* __restrict__ W2T,
    const float* __restrict__ b2, __bf16* __restrict__ Out)
{
  __shared__ __align__(16) char smem[53248];
  __bf16* Hb = (__bf16*)(smem + 36864);

  const int tid = threadIdx.x, l = tid & 63, w = tid >> 6;  // w 0..7
  const int m0 = blockIdx.x * 32;
  const int q4 = (l >> 4) * 4;

  f32x4 acc[2][2];
#pragma unroll
  for (int i = 0; i < 2; ++i)
#pragma unroll
    for (int j = 0; j < 2; ++j) acc[i][j] = (f32x4){0.f, 0.f, 0.f, 0.f};

  const __bf16* Xg = X + (size_t)(m0 + (tid >> 2)) * Dn + (tid & 3) * 8; // tid<128

  auto stageA = [&](int buf, int kt) {
    if (tid < 128)
      async_copy16(Xg + kt * 32, (__bf16*)(smem + buf * 2048) + tid * 8);
  };
  auto stageW = [&](const __bf16* WT, int buf, int kt) {
    __bf16* Wstb = (__bf16*)(smem + 4096 + buf * 16384);
#pragma unroll
    for (int r2 = 0; r2 < 2; ++r2) {
      const int ch = tid + r2 * 512, row = ch >> 2, kk = (ch & 3) * 8;
      async_copy16(WT + (size_t)row * Dn + kt * 32 + kk, Wstb + ch * 8);
    }
  };

  // ---- layer 1 ----
  stageA(0, 0); stageW(W1T, 0, 0);
  __syncthreads();
  for (int kt = 0; kt < 8; ++kt) {
    if (kt < 7) { stageA((kt + 1) & 1, kt + 1); stageW(W1T, (kt + 1) & 1, kt + 1); }
    const __bf16* Astb = (const __bf16*)(smem + (kt & 1) * 2048);
    const __bf16* Wstb = (const __bf16*)(smem + 4096 + (kt & 1) * 16384);
    bf16_8 bf[2];
#pragma unroll
    for (int j = 0; j < 2; ++j)
      bf[j] = *(const bf16_8*)(Wstb + (w * 32 + j * 16 + (l & 15)) * 32 + (l >> 4) * 8);
#pragma unroll
    for (int i = 0; i < 2; ++i) {
      bf16_8 af = *(const bf16_8*)(Astb + (i * 16 + (l & 15)) * 32 + (l >> 4) * 8);
#pragma unroll
      for (int j = 0; j < 2; ++j)
        acc[i][j] = __builtin_amdgcn_mfma_f32_16x16x32_bf16(af, bf[j], acc[i][j], 0, 0, 0);
    }
    __syncthreads();
  }

  // h = relu(acc + b1) -> pre-tiled LDS [kt][32][32]
#pragma unroll
  for (int j = 0; j < 2; ++j) {
    const int col = w * 32 + j * 16 + (l & 15);
    const float bj = b1[col];
    __bf16* hc = Hb + (col >> 5) * 1024 + (col & 31);
#pragma unroll
    for (int i = 0; i < 2; ++i)
#pragma unroll
      for (int r = 0; r < 4; ++r) {
        const int row = i * 16 + q4 + r;
        hc[row * 32] = (__bf16)fmaxf(acc[i][j][r] + bj, 0.0f);
      }
  }
  __syncthreads();

  // ---- layer 2 ----
#pragma unroll
  for (int i = 0; i < 2; ++i)
#pragma unroll
    for (int j = 0; j < 2; ++j) acc[i][j] = (f32x4){0.f, 0.f, 0.f, 0.f};
  stageW(W2T, 0, 0);
  __syncthreads();
  for (int kt = 0; kt < 8; ++kt) {
    if (kt < 7) stageW(W2T, (kt + 1) & 1, kt + 1);
    const __bf16* Wstb = (const __bf16*)(smem + 4096 + (kt & 1) * 16384);
    bf16_8 bf[2];
#pragma unroll
    for (int j = 0; j < 2; ++j)
      bf[j] = *(const bf16_8*)(Wstb + (w * 32 + j * 16 + (l & 15)) * 32 + (l >> 4) * 8);
#pragma unroll
    for (int i = 0; i < 2; ++i) {
      bf16_8 af = *(const bf16_8*)(Hb + kt * 1024 + (i * 16 + (l & 15)) * 32 + (l >> 4) * 8);
#pragma unroll
      for (int j = 0; j < 2; ++j)
        acc[i][j] = __builtin_amdgcn_mfma_f32_16x16x32_bf16(af, bf[j], acc[i][j], 0, 0, 0);
    }
    __syncthreads();
  }

#pragma unroll
  for (int j = 0; j < 2; ++j) {
    const int col = w * 32 + j * 16 + (l & 15);
    const float bj = b2[col];
#pragma unroll
    for (int i = 0; i < 2; ++i)
#pragma unroll
      for (int r = 0; r < 4; ++r) {
        const int row = i * 16 + q4 + r;
        Out[(size_t)(m0 + row) * Dn + col] = (__bf16)(acc[i][j][r] + bj);
      }
  }
}

// ---- fused c-MLP + s-MLP + elementwise update (iterations 1..4) ------------
// R12 row-major version (proven; good global coalescing).
__global__ __launch_bounds__(512) void mlp2_cs(
    __bf16* __restrict__ S,
    const __bf16* __restrict__ sW1T, const float* __restrict__ sb1,
    const __bf16* __restrict__ sW2T, const float* __restrict__ sb2,
    const __bf16* __restrict__ cW1T, const float* __restrict__ cb1,
    const __bf16* __restrict__ cW2T, const float* __restrict__ cb2,
    __bf16* __restrict__ C)
{
  __shared__ __align__(16) char smem[71680];
  __bf16* Hb    = (__bf16*)(smem + 22528);
  __bf16* Snew  = (__bf16*)smem;
  __bf16* Hc    = (__bf16*)(smem + 45056);
  __bf16* CnewL = (__bf16*)(smem + 53248);

  const int tid = threadIdx.x, l = tid & 63, w = tid >> 6;  // w 0..7
  const int m0  = blockIdx.x * 96;
  const int ba0 = blockIdx.x * 16;
  const int q4  = (l >> 4) * 4;

  // ===================== Phase C: cnew = mlp_c(C[16 rows]) ==================
  {
    f32x4 ac[2];
    ac[0] = (f32x4){0.f, 0.f, 0.f, 0.f};
    ac[1] = (f32x4){0.f, 0.f, 0.f, 0.f};

    const __bf16* Cg = C + (size_t)(ba0 + (tid >> 2)) * Dn + (tid & 3) * 8; // tid<64

    auto stageC1 = [&](int buf, int kt) {
      __bf16* Astb = (__bf16*)(smem + buf * 22528);
      __bf16* Wstb = Astb + 3072;
      if (tid < 64) async_copy16(Cg + kt * 32, Astb + tid * 8);
#pragma unroll
      for (int r2 = 0; r2 < 2; ++r2) {
        const int ch = tid + r2 * 512, row = ch >> 2, kk = (ch & 3) * 8;
        async_copy16(cW1T + (size_t)row * Dn + kt * 32 + kk, Wstb + ch * 8);
      }
    };
    stageC1(0, 0);
    __syncthreads();
    for (int kt = 0; kt < 8; ++kt) {
      if (kt < 7) stageC1((kt + 1) & 1, kt + 1);
      const __bf16* Astb = (const __bf16*)(smem + (kt & 1) * 22528);
      const __bf16* Wstb = Astb + 3072;
      bf16_8 bf[2];
#pragma unroll
      for (int j = 0; j < 2; ++j)
        bf[j] = *(const bf16_8*)(Wstb + (w * 32 + j * 16 + (l & 15)) * 32 + (l >> 4) * 8);
      bf16_8 af = *(const bf16_8*)(Astb + (l & 15) * 32 + (l >> 4) * 8);
#pragma unroll
      for (int j = 0; j < 2; ++j)
        ac[j] = __builtin_amdgcn_mfma_f32_16x16x32_bf16(af, bf[j], ac[j], 0, 0, 0);
      __syncthreads();
    }

#pragma unroll
    for (int j = 0; j < 2; ++j) {
      const int col = w * 32 + j * 16 + (l & 15);
      const float bj = cb1[col];
      __bf16* hc = Hc + (col >> 5) * 512 + (col & 31);
#pragma unroll
      for (int r = 0; r < 4; ++r)
        hc[(q4 + r) * 32] = (__bf16)fmaxf(ac[j][r] + bj, 0.0f);
    }
    __syncthreads();

    ac[0] = (f32x4){0.f, 0.f, 0.f, 0.f};
    ac[1] = (f32x4){0.f, 0.f, 0.f, 0.f};
    auto stageC2 = [&](int buf, int kt) {
      __bf16* Wstb = (__bf16*)(smem + buf * 22528 + 6144);
#pragma unroll
      for (int r2 = 0; r2 < 2; ++r2) {
        const int ch = tid + r2 * 512, row = ch >> 2, kk = (ch & 3) * 8;
        async_copy16(cW2T + (size_t)row * Dn + kt * 32 + kk, Wstb + ch * 8);
      }
    };
    stageC2(0, 0);
    __syncthreads();
    for (int kt = 0; kt < 8; ++kt) {
      if (kt < 7) stageC2((kt + 1) & 1, kt + 1);
      const __bf16* Wstb = (const __bf16*)(smem + (kt & 1) * 22528 + 6144);
      bf16_8 bf[2];
#pragma unroll
      for (int j = 0; j < 2; ++j)
        bf[j] = *(const bf16_8*)(Wstb + (w * 32 + j * 16 + (l & 15)) * 32 + (l >> 4) * 8);
      bf16_8 af = *(const bf16_8*)(Hc + kt * 512 + (l & 15) * 32 + (l >> 4) * 8);
#pragma unroll
      for (int j = 0; j < 2; ++j)
        ac[j] = __builtin_amdgcn_mfma_f32_16x16x32_bf16(af, bf[j], ac[j], 0, 0, 0);
      __syncthreads();
    }

#pragma unroll
    for (int j = 0; j < 2; ++j) {
      const int col = w * 32 + j * 16 + (l & 15);
      const float bj = cb2[col];
#pragma unroll
      for (int r = 0; r < 4; ++r)
        CnewL[(q4 + r) * 264 + col] = (__bf16)(ac[j][r] + bj);
    }
    __syncthreads();
  }

  bf16_8 cn8 = *(const bf16_8*)(CnewL + (tid >> 5) * 264 + (tid & 31) * 8);

  // ===================== Phase S: s-MLP + update ============================
  f32x4 acc[6][2];
#pragma unroll
  for (int i = 0; i < 6; ++i)
#pragma unroll
    for (int j = 0; j < 2; ++j) acc[i][j] = (f32x4){0.f, 0.f, 0.f, 0.f};

  const __bf16* Sg = S + (size_t)(m0 + (tid >> 2)) * Dn + (tid & 3) * 8; // tid<384

  auto stageL1 = [&](int buf, int kt) {
    __bf16* Astb = (__bf16*)(smem + buf * 22528);
    __bf16* Wstb = (__bf16*)(smem + buf * 22528 + 6144);
    if (tid < 384) async_copy16(Sg + kt * 32, Astb + tid * 8);
#pragma unroll
    for (int r2 = 0; r2 < 2; ++r2) {
      const int ch = tid + r2 * 512, row = ch >> 2, kk = (ch & 3) * 8;
      async_copy16(sW1T + (size_t)row * Dn + kt * 32 + kk, Wstb + ch * 8);
    }
  };

  stageL1(0, 0);
  __syncthreads();
  for (int kt = 0; kt < 8; ++kt) {
    if (kt < 7) stageL1((kt + 1) & 1, kt + 1);
    const __bf16* Astb = (const __bf16*)(smem + (kt & 1) * 22528);
    const __bf16* Wstb = Astb + 3072;
    bf16_8 bf[2];
#pragma unroll
    for (int j = 0; j < 2; ++j)
      bf[j] = *(const bf16_8*)(Wstb + (w * 32 + j * 16 + (l & 15)) * 32 + (l >> 4) * 8);
#pragma unroll
    for (int i = 0; i < 6; ++i) {
      bf16_8 af = *(const bf16_8*)(Astb + (i * 16 + (l & 15)) * 32 + (l >> 4) * 8);
#pragma unroll
      for (int j = 0; j < 2; ++j)
        acc[i][j] = __builtin_amdgcn_mfma_f32_16x16x32_bf16(af, bf[j], acc[i][j], 0, 0, 0);
    }
    __syncthreads();
  }

#pragma unroll
  for (int j = 0; j < 2; ++j) {
    const int col = w * 32 + j * 16 + (l & 15);
    const float bj = sb1[col];
    __bf16* hc = Hb + (col >> 5) * (96 * 32) + (col & 31);
#pragma unroll
    for (int i = 0; i < 6; ++i)
#pragma unroll
      for (int r = 0; r < 4; ++r) {
        const int row = i * 16 + q4 + r;
        hc[row * 32] = (__bf16)fmaxf(acc[i][j][r] + bj, 0.0f);
      }
  }
  __syncthreads();

#pragma unroll
  for (int i = 0; i < 6; ++i)
#pragma unroll
    for (int j = 0; j < 2; ++j) acc[i][j] = (f32x4){0.f, 0.f, 0.f, 0.f};
  __bf16* Wst = (__bf16*)(smem + 6144);
  for (int kt = 0; kt < 8; ++kt) {
#pragma unroll
    for (int r2 = 0; r2 < 2; ++r2) {
      const int ch = tid + r2 * 512, row = ch >> 2, kk = (ch & 3) * 8;
      async_copy16(sW2T + (size_t)row * Dn + kt * 32 + kk, Wst + ch * 8);
    }
    __syncthreads();
    bf16_8 bf[2];
#pragma unroll
    for (int j = 0; j < 2; ++j)
      bf[j] = *(const bf16_8*)(Wst + (w * 32 + j * 16 + (l & 15)) * 32 + (l >> 4) * 8);
#pragma unroll
    for (int i = 0; i < 6; ++i) {
      bf16_8 af = *(const bf16_8*)(Hb + kt * (96 * 32) + (i * 16 + (l & 15)) * 32 + (l >> 4) * 8);
#pragma unroll
      for (int j = 0; j < 2; ++j)
        acc[i][j] = __builtin_amdgcn_mfma_f32_16x16x32_bf16(af, bf[j], acc[i][j], 0, 0, 0);
    }
    __syncthreads();
  }

#pragma unroll
  for (int j = 0; j < 2; ++j) {
    const int col = w * 32 + j * 16 + (l & 15);
    const float bj = sb2[col];
#pragma unroll
    for (int i = 0; i < 6; ++i)
#pragma unroll
      for (int r = 0; r < 4; ++r) {
        const int row = i * 16 + q4 + r;
        Snew[row * 264 + col] = (__bf16)(acc[i][j][r] + bj);
      }
  }
  __syncthreads();

  {
    const int ba = tid >> 5, dg = (tid & 31) * 8;
    const size_t gb = (size_t)(ba0 + ba) * Dn + dg;
    float cn[8], m[8];
#pragma unroll
    for (int e = 0; e < 8; ++e) { cn[e] = (float)cn8[e]; m[e] = -3.402823466e38f; }
#pragma unroll
    for (int t = 0; t < Tn; ++t) {
      const int row = ba * 6 + t;
      bf16_8 sn8 = *(const bf16_8*)(Snew + row * 264 + dg);
      const size_t gs = (size_t)(m0 + row) * Dn + dg;
      bf16_8 s8 = *(const bf16_8*)(S + gs);
      bf16_8 o8;
#pragma unroll
      for (int e = 0; e < 8; ++e) {
        const float sn = (float)sn8[e] * cn[e];
        m[e] = fmaxf(m[e], sn);
        o8[e] = (__bf16)(kAlpha * (float)s8[e] + kBeta * sn);
      }
      *(bf16_8*)(S + gs) = o8;
    }
    bf16_8 c8 = *(const bf16_8*)(C + gb);
#pragma unroll
    for (int e = 0; e < 8; ++e)
      c8[e] = (__bf16)(kAlpha * (float)c8[e] + kBeta * m[e]);
    *(bf16_8*)(C + gb) = c8;
  }
}

// ---- fully fused decoder v4: R12 GEMM phase + coalesced epilogue -----------
// BM=64, 512 thr, grid 768, launch_bounds(512,4), LDS 72KB -> 2 blocks/CU.
__global__ __launch_bounds__(512, 4) void decoder_fused(
    const __bf16* __restrict__ S, const __bf16* __restrict__ W1T,
    const float* __restrict__ b1, const __bf16* __restrict__ W2T,
    const float* __restrict__ bias, float* __restrict__ out)
{
  __shared__ __align__(16) char smem[73728];
  __bf16* Ast = (__bf16*)smem;             // [8kt][64][32]  32KB  (S tile)
  __bf16* W1s = (__bf16*)(smem + 32768);   // [8kt][64][32]  32KB  (W1 chunk)
  __bf16* Hb  = (__bf16*)(smem + 65536);   // [2kt2][64][32]  8KB
  float*  mid = (float*)smem;              // epilogue overlay (30.8KB)
  float*  coordL = (float*)(smem + 32768); // epilogue overlay [32][160] 20.5KB

  const int tid = threadIdx.x, l = tid & 63, w = tid >> 6;  // w 0..7
  const int m0 = blockIdx.x * 64;
  const int q4 = (l >> 4) * 4;
  const int rt  = w >> 1;                  // L1 row-tile (0..3)
  const int ch2 = (w & 1) * 32;            // L1 col-half base

  f32x4 acc[4][4];                         // persistent 64x512 output tile
#pragma unroll
  for (int i = 0; i < 4; ++i)
#pragma unroll
    for (int j = 0; j < 4; ++j) acc[i][j] = (f32x4){0.f, 0.f, 0.f, 0.f};

  // stage whole S tile pre-tiled [kt][64][32] (2048 x 16B chunks)
#pragma unroll
  for (int r4 = 0; r4 < 4; ++r4) {
    const int q = tid + r4 * 512;
    const int ktq = q >> 8, row = (q >> 2) & 63, kk = (q & 3) * 8;
    async_copy16(S + (size_t)(m0 + row) * Dn + ktq * 32 + kk, Ast + q * 8);
  }

  // stage whole 64x256 W1 chunk pre-tiled [kt][64][32]
  auto stageW1 = [&](int cc) {
#pragma unroll
    for (int r4 = 0; r4 < 4; ++r4) {
      const int q = tid + r4 * 512;
      const int ktq = q >> 8, row = (q >> 2) & 63, kk = (q & 3) * 8;
      async_copy16(W1T + (size_t)(cc * 64 + row) * Dn + ktq * 32 + kk, W1s + q * 8);
    }
  };

  // fixed per-thread W2T column pointers (4 output cols per thread)
  const __bf16* W2p[4];
#pragma unroll
  for (int j = 0; j < 4; ++j) {
    int col = w * 64 + j * 16 + (l & 15);
    if (col > 400) col = 400;
    W2p[j] = W2T + (size_t)col * Hn + (l >> 4) * 8;
  }

  stageW1(0);
  __syncthreads();                          // Ast + W1s(0) resident

  for (int cc = 0; cc < 8; ++cc) {
    // ---- L1: 16 barrier-free MFMAs ----
    f32x4 a1[2];
    a1[0] = (f32x4){0.f, 0.f, 0.f, 0.f};
    a1[1] = (f32x4){0.f, 0.f, 0.f, 0.f};
#pragma unroll
    for (int kt = 0; kt < 8; ++kt) {
      bf16_8 af = *(const bf16_8*)(Ast + kt * 2048 + (rt * 16 + (l & 15)) * 32 + (l >> 4) * 8);
#pragma unroll
      for (int j = 0; j < 2; ++j) {
        bf16_8 bw = *(const bf16_8*)(W1s + kt * 2048 + (ch2 + j * 16 + (l & 15)) * 32 + (l >> 4) * 8);
        a1[j] = __builtin_amdgcn_mfma_f32_16x16x32_bf16(af, bw, a1[j], 0, 0, 0);
      }
    }

    // Hb write (bias + relu), pre-tiled [kt2][64][32]
#pragma unroll
    for (int j = 0; j < 2; ++j) {
      const int col = ch2 + j * 16 + (l & 15);
      const float bj = b1[cc * 64 + col];
      __bf16* hp = Hb + (col >> 5) * 2048 + (col & 31);
#pragma unroll
      for (int r = 0; r < 4; ++r)
        hp[(rt * 16 + q4 + r) * 32] = (__bf16)fmaxf(a1[j][r] + bj, 0.0f);
    }
    __syncthreads();                        // (A) W1s free; Hb visible

    if (cc < 7) stageW1(cc + 1);            // async, hidden under L2

    // ---- L2 partial accumulate (K=64); B-frags from L2-hot W2T ----
#pragma unroll
    for (int kt2 = 0; kt2 < 2; ++kt2) {
      bf16_8 af2[4], bf2[4];
#pragma unroll
      for (int j = 0; j < 4; ++j)
        bf2[j] = *(const bf16_8*)(W2p[j] + cc * 64 + kt2 * 32);
#pragma unroll
      for (int i = 0; i < 4; ++i)
        af2[i] = *(const bf16_8*)(Hb + kt2 * 2048 + (i * 16 + (l & 15)) * 32 + (l >> 4) * 8);
#pragma unroll
      for (int i = 0; i < 4; ++i)
#pragma unroll
        for (int j = 0; j < 4; ++j)
          acc[i][j] = __builtin_amdgcn_mfma_f32_16x16x32_bf16(af2[i], bf2[j], acc[i][j], 0, 0, 0);
    }
    __syncthreads();                        // (B) Hb reads done; W1s(cc+1) drained
  }

  // ---- epilogue v2: LDS-staged, fully-coalesced coordinate writes ----
  float* cov    = out + MR + (size_t)MR * 160;
  float* coordG = out + MR;
  const int gc = w * 64 + (l & 15);
#pragma unroll
  for (int sub = 0; sub < 2; ++sub) {
#pragma unroll
    for (int ih = 0; ih < 2; ++ih) {
      const int i = sub * 2 + ih;
#pragma unroll
      for (int j = 0; j < 4; ++j) {
        const int c = gc + j * 16;
        if (c > 400) continue;
        const float bj = bias[c];
#pragma unroll
        for (int r = 0; r < 4; ++r) {
          const int lr = ih * 16 + q4 + r;
          const int gr = m0 + sub * 32 + lr;
          const float v = acc[i][j][r] + bj;
          if (c < 160)      coordL[lr * 160 + c] = v;
          else if (c < 400) mid[lr * 241 + (c - 160)] = v;
          else              out[gr] = v;
        }
      }
    }
    __syncthreads();
    // coordinates: 32 rows x 40 f32x4 = 1280 chunks, 640B contiguous per row
#pragma unroll
    for (int p = 0; p < 3; ++p) {
      const int q = p * 512 + tid;
      if (q < 1280) {
        const int r32 = q / 40, c4 = q - r32 * 40;
        const int gr = m0 + sub * 32 + r32;
        *(f32x4*)(coordG + (size_t)gr * 160 + c4 * 4) =
            *(const f32x4*)(coordL + r32 * 160 + c4 * 4);
      }
    }
    // covariance from mid (16B/lane contiguous, unchanged)
#pragma unroll
    for (int p = 0; p < 5; ++p) {
      const int q = p * 512 + tid;
      const int r32 = q / 80, j = q - r32 * 80;
      const int gr = m0 + sub * 32 + r32;
      const float av = mid[r32 * 241 + j];
      const float bv = mid[r32 * 241 + 80 + j];
      const float cv = mid[r32 * 241 + 160 + j];
      const float eb = __expf(bv), ebn = __expf(-bv);
      const float sh = 0.5f * (eb - ebn), ch = 0.5f * (eb + ebn);
      const float ea = __expf(av), ean = __expf(-av), ec = __expf(cv);
      f32x4 c4 = { ea * ch * ec, sh * ec, sh * ec, ean * ch * ec };
      *(f32x4*)(cov + (size_t)gr * 320 + 4 * j) = c4;
    }
    if (sub == 0) __syncthreads();
  }
}

// ---- weight transpose + bf16 convert ---------------------------------------
__global__ __launch_bounds__(256) void transpose_bf16(
    const float* __restrict__ W, __bf16* __restrict__ WT, int K, int N)
{
  __shared__ float t[32][33];
  const int b  = blockIdx.z;
  const int tx = threadIdx.x, ty = threadIdx.y;
  const int k0 = blockIdx.y * 32, n0 = blockIdx.x * 32;
  const float* Wb  = W  + (size_t)b * K * N;
  __bf16*      WTb = WT + (size_t)b * N * K;
#pragma unroll
  for (int r = 0; r < 4; ++r) {
    int kk = k0 + ty + r * 8;
    if (kk < K && n0 + tx < N) t[ty + r * 8][tx] = Wb[(size_t)kk * N + n0 + tx];
  }
  __syncthreads();
#pragma unroll
  for (int r = 0; r < 4; ++r) {
    int nn = n0 + ty + r * 8;
    if (nn < N && k0 + tx < K)
      WTb[(size_t)nn * K + k0 + tx] = (__bf16)t[tx][ty + r * 8];
  }
}

__global__ __launch_bounds__(256) void convert_bf16(
    const float* __restrict__ in, __bf16* __restrict__ out, int n)
{
  int i = blockIdx.x * 256 + threadIdx.x;
  if (i < n) out[i] = (__bf16)in[i];
}

// ---- iter-0 elementwise (init folded) --------------------------------------
__global__ __launch_bounds__(256) void ew_update0(
    const float* __restrict__ anchor, const float* __restrict__ fe,
    const float* __restrict__ snewsm, const __bf16* __restrict__ cnew,
    __bf16* __restrict__ s, __bf16* __restrict__ c)
{
  int q = blockIdx.x * 256 + threadIdx.x;
  if (q >= BA * 32) return;
  int ba = q >> 5;
  int dg = (q & 31) * 8;
  bf16_8 cn8 = *(const bf16_8*)(cnew + (size_t)ba * Dn + dg);
  float cn[8], m[8];
#pragma unroll
  for (int e = 0; e < 8; ++e) { cn[e] = (float)cn8[e]; m[e] = -3.402823466e38f; }
  size_t base = (size_t)ba * Tn * Dn + dg;
#pragma unroll
  for (int t = 0; t < Tn; ++t) {
    bf16_8 o8;
#pragma unroll
    for (int e = 0; e < 8; ++e) {
      float sn = snewsm[t * Dn + dg + e] * cn[e];
      m[e] = fmaxf(m[e], sn);
      o8[e] = (__bf16)(kAlpha * anchor[t * Dn + dg + e] + kBeta * sn);
    }
    *(bf16_8*)(s + base + t * Dn) = o8;
  }
  bf16_8 c8;
#pragma unroll
  for (int e = 0; e < 8; ++e)
    c8[e] = (__bf16)(kAlpha * fe[(size_t)ba * Dn + dg + e] + kBeta * m[e]);
  *(bf16_8*)(c + (size_t)ba * Dn + dg) = c8;
}

// ---------------------------------------------------------------------------
extern "C" void kernel_launch(void* const* d_in, const int* in_sizes, int n_in,
                              void* d_out, int out_size, void* d_ws, size_t ws_size,
                              hipStream_t stream) {
  const float* fe     = (const float*)d_in[0];
  const float* anchor = (const float*)d_in[1];
  const float* sW1 = (const float*)d_in[2];
  const float* sb1 = (const float*)d_in[3];
  const float* sW2 = (const float*)d_in[4];
  const float* sb2 = (const float*)d_in[5];
  const float* cW1 = (const float*)d_in[6];
  const float* cb1 = (const float*)d_in[7];
  const float* cW2 = (const float*)d_in[8];
  const float* cb2 = (const float*)d_in[9];
  const float* dW1 = (const float*)d_in[10];
  const float* db1 = (const float*)d_in[11];
  const float* dW2 = (const float*)d_in[12];
  const float* db2 = (const float*)d_in[13];
  float* out = (float*)d_out;

  // ---- workspace layout (bytes) ----
  char* p = (char*)d_ws;
  __bf16* s_bf    = (__bf16*)(p + 0);            // 25,165,824
  __bf16* c_bf    = (__bf16*)(p + 75497472);     //  4,194,304
  __bf16* cnew_bf = (__bf16*)(p + 79691776);     //  4,194,304
  __bf16* fe_bf   = (__bf16*)(p + 83886080);     //  4,194,304
  __bf16* sWT1    = (__bf16*)(p + 88080384);     //    655,360 each
  __bf16* sWT2    = (__bf16*)(p + 88735744);
  __bf16* cWT1    = (__bf16*)(p + 89391104);
  __bf16* cWT2    = (__bf16*)(p + 90046464);
  __bf16* dWT1    = (__bf16*)(p + 90701824);     //    262,144
  __bf16* dWT2    = (__bf16*)(p + 90963968);     //    410,624
  __bf16* anc_bf  = (__bf16*)(p + 91374592);     //      3,072
  __bf16* hsm_bf  = (__bf16*)(p + 91377664);     //      3,072
  float*  snewsm_f= (float* )(p + 91380736);     //      6,144

  auto gemm = [&](const __bf16* A, const __bf16* BT, const float* b, void* C,
                  int M, int N, int K, bool relu, bool outbf) {
    dim3 grid((N + 127) / 128, (M + 127) / 128);
    if (relu) {
      if (outbf) gemm_mfma<true,  true ><<<grid, 256, 0, stream>>>(A, BT, b, C, M, N, K);
      else       gemm_mfma<true,  false><<<grid, 256, 0, stream>>>(A, BT, b, C, M, N, K);
    } else {
      if (outbf) gemm_mfma<false, true ><<<grid, 256, 0, stream>>>(A, BT, b, C, M, N, K);
      else       gemm_mfma<false, false><<<grid, 256, 0, stream>>>(A, BT, b, C, M, N, K);
    }
  };

  // ---- weight prep ----
  {
    dim3 blk(32, 8);
    dim3 g88(8, 8, NBn);
    transpose_bf16<<<g88, blk, 0, stream>>>(sW1, sWT1, Dn, Dn);
    transpose_bf16<<<g88, blk, 0, stream>>>(sW2, sWT2, Dn, Dn);
    transpose_bf16<<<g88, blk, 0, stream>>>(cW1, cWT1, Dn, Dn);
    transpose_bf16<<<g88, blk, 0, stream>>>(cW2, cWT2, Dn, Dn);
    transpose_bf16<<<dim3(16, 8, 1), blk, 0, stream>>>(dW1, dWT1, Dn, Hn);
    transpose_bf16<<<dim3(13, 16, 1), blk, 0, stream>>>(dW2, dWT2, Hn, OUTn);
  }
  convert_bf16<<<(BA * Dn + 255) / 256, 256, 0, stream>>>(fe, fe_bf, BA * Dn);
  convert_bf16<<<(Tn * Dn + 255) / 256, 256, 0, stream>>>(anchor, anc_bf, Tn * Dn);

  const size_t WKK = (size_t)Dn * Dn;

  // ---- iteration 0 (s-branch on 6 anchor rows; c-branch fused MLP) ----
  gemm(anc_bf, sWT1, sb1, hsm_bf,   Tn, Dn, Dn, true,  true);
  gemm(hsm_bf, sWT2, sb2, snewsm_f, Tn, Dn, Dn, false, false);
  mlp2_c<<<BA / 32, 512, 0, stream>>>(fe_bf, cWT1, cb1, cWT2, cb2, cnew_bf);
  ew_update0<<<(BA * 32 + 255) / 256, 256, 0, stream>>>(anchor, fe, snewsm_f,
                                                        cnew_bf, s_bf, c_bf);

  // ---- iterations 1..4: ONE fused kernel each ----
  for (int i = 1; i < NBn; ++i) {
    mlp2_cs<<<MR / 96, 512, 0, stream>>>(
        s_bf,
        sWT1 + i * WKK, sb1 + i * Dn, sWT2 + i * WKK, sb2 + i * Dn,
        cWT1 + i * WKK, cb1 + i * Dn, cWT2 + i * WKK, cb2 + i * Dn,
        c_bf);
  }

  // ---- fully fused decoder ----
  decoder_fused<<<MR / 64, 512, 0, stream>>>(s_bf, dWT1, db1, dWT2, db2, out);
}